// Round 7
// baseline (84.058 us; speedup 1.0000x reference)
//
#include <hip/hip_runtime.h>
#include <math.h>

// ---- problem constants ----
#define B_N    2
#define S_LEN  2048
#define DMODEL 192
#define HQ_N   8
#define HKV_N  4
#define DH_N   24
#define KAUG   160   // 24 q/k + 64 cos + 64 sin + 8 zero pad (= 10 * 16)
#define LOG2E  1.44269504088896340736f

typedef __attribute__((ext_vector_type(8)))  short bf16x8;
typedef __attribute__((ext_vector_type(4)))  float f32x4;
typedef __attribute__((ext_vector_type(16))) float f32x16;

static __device__ __forceinline__ unsigned short f2bf(float f) {
    union { float f; unsigned u; } v; v.f = f;
    unsigned r = v.u + 0x7FFFu + ((v.u >> 16) & 1u);
    return (unsigned short)(r >> 16);
}
static __device__ __forceinline__ unsigned pk2(float a, float b) {
    return (unsigned)f2bf(a) | ((unsigned)f2bf(b) << 16);
}
static __device__ __forceinline__ unsigned cvtpk_bf16(float a, float b) {
    unsigned r;
    asm("v_cvt_pk_bf16_f32 %0, %1, %2" : "=v"(r) : "v"(a), "v"(b));
    return r;
}

typedef __attribute__((address_space(3))) unsigned short lds_us;
typedef const __attribute__((address_space(1))) unsigned short glb_us;
static __device__ __forceinline__ void gld16(const unsigned short* g, unsigned short* l) {
    __builtin_amdgcn_global_load_lds((glb_us*)g, (lds_us*)l, 16, 0, 0);
}

// ============================================================
// K1: prep — blocks [0,384): QKV GEMM (f32->bf16 staged, MFMA);
// blocks [384,896): phase sincos -> QA/KA sections + pads;
// blocks [896,904): VT pad rows.   (identical to R5's passing code)
// ============================================================
__global__ __launch_bounds__(256) void prep_kernel(
    const float* __restrict__ x, const float* __restrict__ Wq,
    const float* __restrict__ Wkv, const float* __restrict__ alpha_p,
    const float* __restrict__ beta_p,
    unsigned short* __restrict__ QA, unsigned short* __restrict__ KA,
    unsigned short* __restrict__ VT)
{
    __shared__ __align__(16) unsigned short a_lds[64][200];
    __shared__ __align__(16) unsigned short b_lds[64][200];
    const int blk = blockIdx.x, tid = threadIdx.x;

    if (blk < 384) {
        const int wid = tid >> 6, lane = tid & 63, g = lane >> 4, lr = lane & 15;
        const int brow = (blk & 63) * 64;
        const int bcol = (blk >> 6) * 64;

        #pragma unroll
        for (int c = 0; c < 12; ++c) {
            int idx = c * 256 + tid;
            int r = idx / 48, ch = idx % 48;
            float4 v = *(const float4*)&x[(size_t)(brow + r) * 192 + ch * 4];
            uint2 w; w.x = pk2(v.x, v.y); w.y = pk2(v.z, v.w);
            *(uint2*)&a_lds[r][ch * 4] = w;
            int wr = bcol + r;
            const float* wsrc = (wr < 192) ? &Wq[(size_t)wr * 192 + ch * 4]
                                           : &Wkv[(size_t)(wr - 192) * 192 + ch * 4];
            float4 wv = *(const float4*)wsrc;
            uint2 w2; w2.x = pk2(wv.x, wv.y); w2.y = pk2(wv.z, wv.w);
            *(uint2*)&b_lds[r][ch * 4] = w2;
        }
        __syncthreads();

        f32x4 acc[4];
        #pragma unroll
        for (int nc = 0; nc < 4; ++nc) acc[nc] = (f32x4){0.f, 0.f, 0.f, 0.f};
        #pragma unroll
        for (int kc = 0; kc < 6; ++kc) {
            bf16x8 af = *(const bf16x8*)&a_lds[wid * 16 + lr][kc * 32 + g * 8];
            #pragma unroll
            for (int nc = 0; nc < 4; ++nc) {
                bf16x8 bfr = *(const bf16x8*)&b_lds[nc * 16 + lr][kc * 32 + g * 8];
                acc[nc] = __builtin_amdgcn_mfma_f32_16x16x32_bf16(af, bfr, acc[nc], 0, 0, 0);
            }
        }

        const float qs = alpha_p[0] * 0.20412414523193150818f * LOG2E;
        #pragma unroll
        for (int nc = 0; nc < 4; ++nc) {
            int c = bcol + nc * 16 + lr;
            #pragma unroll
            for (int r = 0; r < 4; ++r) {
                int row = brow + wid * 16 + g * 4 + r;
                int b = row >> 11, s = row & (S_LEN - 1);
                float v = acc[nc][r];
                if (c < 192) {
                    int h = c / 24, d = c - 24 * h;
                    QA[((size_t)(b * 8 + h) * S_LEN + s) * KAUG + d] = f2bf(v * qs);
                } else if (c < 288) {
                    int cc = c - 192, kvh = cc / 24, d = cc - 24 * kvh;
                    KA[((size_t)(b * 4 + kvh) * S_LEN + s) * KAUG + d] = f2bf(v);
                } else {
                    int cc = c - 288, kvh = cc / 24, d = cc - 24 * kvh;
                    VT[((size_t)(b * 4 + kvh) * 32 + d) * S_LEN + s] = f2bf(v);
                }
            }
        }
    } else if (blk < 896) {
        const int pblk = blk - 384;
        const int r = tid >> 5, i = tid & 31;
        const int row = pblk * 8 + r;
        const int b = row >> 11, s = row & (S_LEN - 1);
        const float bf = beta_p[0] * (1.0f / 64.0f) * LOG2E;
        float2 p = *(const float2*)&x[(size_t)row * DMODEL + 128 + 2 * i];
        float s0, c0, s1, c1;
        sincosf(p.x, &s0, &c0);
        sincosf(p.y, &s1, &c1);
        unsigned kc_ = pk2(c0, c1), ks_ = pk2(s0, s1);
        unsigned qc_ = pk2(c0 * bf, c1 * bf), qs_ = pk2(s0 * bf, s1 * bf);
        #pragma unroll
        for (int h = 0; h < 8; ++h) {
            unsigned short* base = QA + ((size_t)(b * 8 + h) * S_LEN + s) * KAUG;
            *(unsigned*)(base + 24 + 2 * i) = qc_;
            *(unsigned*)(base + 88 + 2 * i) = qs_;
        }
        #pragma unroll
        for (int kvh = 0; kvh < 4; ++kvh) {
            unsigned short* base = KA + ((size_t)(b * 4 + kvh) * S_LEN + s) * KAUG;
            *(unsigned*)(base + 24 + 2 * i) = kc_;
            *(unsigned*)(base + 88 + 2 * i) = ks_;
        }
        if (i < 12) {
            uint4 z = {0u, 0u, 0u, 0u};
            unsigned short* base = (i < 8)
                ? QA + ((size_t)(b * 8 + i) * S_LEN + s) * KAUG
                : KA + ((size_t)(b * 4 + (i - 8)) * S_LEN + s) * KAUG;
            *(uint4*)(base + 152) = z;
        }
    } else {
        const int j = blk - 896;
        unsigned short* base = VT + ((size_t)j * 32 + 24) * S_LEN;
        uint4 z = {0u, 0u, 0u, 0u};
        #pragma unroll
        for (int c = 0; c < 8; ++c)
            *(uint4*)(base + (size_t)(c * 256 + tid) * 8) = z;
    }
}

// ============================================================
// K2: fused flash attention — 1-wave blocks, barrier-free.
// Grid = 512 x 64 threads.  bid&7 = (b,kvh) -> XCD group.
// i=bid>>3 in 0..63: h = 2kvh + (i>>5), pp = i&31.
// Block serializes TWO 32-row q-subtiles: sA=63-pp then sB=pp
// -> exactly 33 iterations per block (perfect balance, no dup).
// Triple-buffered LDS (72KB), counted vmcnt(24), no s_barrier.
// Pipelined: QK(tile j+1) issued before softmax(j)+PV(j) so the
// softmax VALU chain hides in the MFMA shadow.
// Cross-half reductions via __shfl_xor(.,32) (R5-proven).
// ============================================================
__global__ __launch_bounds__(64) void attn_kernel(
    const unsigned short* __restrict__ QA, const unsigned short* __restrict__ KA,
    const unsigned short* __restrict__ VT, unsigned short* __restrict__ Ob)
{
    __shared__ __align__(16) unsigned short ka_lds[3][64 * KAUG]; // 3 x 20 KiB
    __shared__ __align__(16) unsigned short vt_lds[3][32 * 64];   // 3 x 4 KiB

    const int lane = threadIdx.x & 63;
    const int hi = lane >> 5, c31 = lane & 31;
    const int rs = c31 & 7, w2 = (c31 >> 1) & 3;

    const int bid = blockIdx.x;
    const int grp = bid & 7;                 // XCD group = (b,kvh)
    const int b = grp >> 2, kvh = grp & 3;
    const int i = bid >> 3;                  // 0..63
    const int h = 2 * kvh + (i >> 5);
    const int pp = i & 31;                   // 0..31
    const int sA = 63 - pp, sB = pp;         // two 32-row q-subtiles
    const int nA = (sA >> 1) + 1;            // iters for subtile A (17..32)
    const int NT = 33;                       // nA + nB == 33 always

    const int qrowA = sA * 32 + c31;
    const int qrowB = sB * 32 + c31;
    const int qcA = (sA & 1) * 32 + c31;
    const int qcB = (sB & 1) * 32 + c31;

    const unsigned short* ka_g = KA + (size_t)(b * 4 + kvh) * S_LEN * KAUG;
    const unsigned short* vt_g = VT + (size_t)(b * 4 + kvh) * 32 * S_LEN;

    bf16x8 qf[10];
    auto LOADQF = [&](int qrow) {
        const unsigned short* qa = QA + ((size_t)(b * 8 + h) * S_LEN + qrow) * KAUG + hi * 8;
        #pragma unroll
        for (int kc = 0; kc < 10; ++kc) qf[kc] = *(const bf16x8*)(qa + kc * 16);
    };

    // ---- staging source offsets (pre-swizzled; dest is linear lane*16) ----
    int ka_soff[20];
    #pragma unroll
    for (int u = 0; u < 20; ++u) {
        int idx8 = u * 64 + lane;                    // granule index 0..1279
        int row = idx8 / 20, colg = idx8 % 20;
        int g2 = (colg < 16) ? (colg ^ (row & 7))
                             : (16 + ((colg & 3) ^ ((row >> 1) & 3)));
        ka_soff[u] = row * KAUG + g2 * 8;
    }
    int vt_soff[4];
    #pragma unroll
    for (int u = 0; u < 4; ++u) {
        int idx8 = u * 64 + lane;                    // 0..255
        int row = idx8 >> 3, colg = idx8 & 7;
        vt_soff[u] = row * S_LEN + (colg ^ (row & 7)) * 8;
    }

    // ---- ds_read offsets (swizzled), tile-invariant ----
    unsigned offA[10], offV[4];
    #pragma unroll
    for (int kc = 0; kc < 10; ++kc) {
        int g = 2 * kc + hi;
        int pg = (kc < 8) ? (g ^ rs) : (16 + ((g & 3) ^ w2));
        offA[kc] = c31 * KAUG + pg * 8;
    }
    #pragma unroll
    for (int ks = 0; ks < 4; ++ks)
        offV[ks] = c31 * 64 + ((2 * ks + hi) ^ rs) * 8;

    auto STAGE = [&](int bufsel, int ktile) {
        const int n0 = ktile * 64;
        const unsigned short* kg = ka_g + (size_t)n0 * KAUG;
        unsigned short* kd = &ka_lds[bufsel][0];
        #pragma unroll
        for (int u = 0; u < 20; ++u)
            gld16(kg + ka_soff[u], kd + u * 512 + lane * 8);
        unsigned short* vd = &vt_lds[bufsel][0];
        #pragma unroll
        for (int u = 0; u < 4; ++u)
            gld16(vt_g + n0 + vt_soff[u], vd + u * 512 + lane * 8);
    };

    auto QKTILE = [&](int bufsel, f32x16& o0, f32x16& o1) {
        const unsigned short* kb = &ka_lds[bufsel][0];
        o0 = (f32x16){0,0,0,0,0,0,0,0,0,0,0,0,0,0,0,0};
        o1 = (f32x16){0,0,0,0,0,0,0,0,0,0,0,0,0,0,0,0};
        #pragma unroll
        for (int kc = 0; kc < 10; ++kc) {
            bf16x8 a0 = *(const bf16x8*)(kb + offA[kc]);
            bf16x8 a1 = *(const bf16x8*)(kb + offA[kc] + 32 * KAUG);
            o0 = __builtin_amdgcn_mfma_f32_32x32x16_bf16(a0, qf[kc], o0, 0, 0, 0);
            o1 = __builtin_amdgcn_mfma_f32_32x32x16_bf16(a1, qf[kc], o1, 0, 0, 0);
        }
    };

    f32x16 acc = {0,0,0,0,0,0,0,0,0,0,0,0,0,0,0,0};
    float m = -1e30f, l = 0.f;

    auto EMIT = [&](int qrow) {
        const float invl = 1.0f / l;
        unsigned short* ob = Ob + ((size_t)b * S_LEN + qrow) * DMODEL + h * 24 + 4 * hi;
        #pragma unroll
        for (int k = 0; k < 3; ++k) {
            unsigned u0 = pk2(acc[4 * k] * invl,     acc[4 * k + 1] * invl);
            unsigned u1 = pk2(acc[4 * k + 2] * invl, acc[4 * k + 3] * invl);
            *(unsigned*)(ob + 8 * k)     = u0;
            *(unsigned*)(ob + 8 * k + 2) = u1;
        }
    };

    // ---- prologue: Q(A), stage tiles 0..2, compute S(tile 0) ----
    LOADQF(qrowA);
    STAGE(0, 0); STAGE(1, 1); STAGE(2, 2);          // NT=33 >= 3 always
    asm volatile("s_waitcnt vmcnt(48)" ::: "memory"); // qf + STAGE0 complete
    f32x16 sc0, sc1, sn0, sn1;
    QKTILE(0, sc0, sc1);

    int bcur = 0;
    for (int j = 0; j < NT; ++j) {
        int bnxt = bcur + 1; if (bnxt == 3) bnxt = 0;

        // ---- QK for tile j+1 (MFMA pipe; softmax below overlaps) ----
        if (j + 1 < NT) {
            if (j + 2 < NT) asm volatile("s_waitcnt vmcnt(24)" ::: "memory");
            else            asm volatile("s_waitcnt vmcnt(0)"  ::: "memory");
            QKTILE(bnxt, sn0, sn1);
        }

        // ---- causal mask on the two diagonal iterations ----
        if (j == nA - 1 || j == NT - 1) {
            const int qc = (j == nA - 1) ? qcA : qcB;
            #pragma unroll
            for (int r = 0; r < 16; ++r) {
                int krow = (r & 3) + 8 * (r >> 2) + 4 * hi;
                if (krow > qc)      sc0[r] = -1e30f;
                if (krow + 32 > qc) sc1[r] = -1e30f;
            }
        }

        // ---- online softmax (tree max + shfl cross-half, defer-max) ----
        float t8[8];
        #pragma unroll
        for (int r = 0; r < 8; ++r)
            t8[r] = fmaxf(fmaxf(sc0[r], sc0[r + 8]), fmaxf(sc1[r], sc1[r + 8]));
        float t4a = fmaxf(t8[0], t8[4]), t4b = fmaxf(t8[1], t8[5]);
        float t4c = fmaxf(t8[2], t8[6]), t4d = fmaxf(t8[3], t8[7]);
        float tmax = fmaxf(fmaxf(t4a, t4b), fmaxf(t4c, t4d));
        tmax = fmaxf(tmax, __shfl_xor(tmax, 32, 64));
        if (!__all(tmax <= m + 8.f)) {
            float mnew = fmaxf(m, tmax);
            float corr = __builtin_amdgcn_exp2f(m - mnew);
            m = mnew;
            l *= corr;
            #pragma unroll
            for (int r = 0; r < 16; ++r) acc[r] *= corr;
        }
        #pragma unroll
        for (int r = 0; r < 16; ++r) {
            sc0[r] = __builtin_amdgcn_exp2f(sc0[r] - m);
            sc1[r] = __builtin_amdgcn_exp2f(sc1[r] - m);
        }
        float u8[8];
        #pragma unroll
        for (int r = 0; r < 8; ++r)
            u8[r] = (sc0[r] + sc0[r + 8]) + (sc1[r] + sc1[r + 8]);
        float u4a = u8[0] + u8[4], u4b = u8[1] + u8[5];
        float u4c = u8[2] + u8[6], u4d = u8[3] + u8[7];
        float ts = (u4a + u4b) + (u4c + u4d);
        ts += __shfl_xor(ts, 32, 64);
        l += ts;

        // ---- pack P and PV (A = V^T from LDS buf bcur) ----
        unsigned W0[8], W1[8];
        #pragma unroll
        for (int jj = 0; jj < 8; ++jj) {
            W0[jj] = cvtpk_bf16(sc0[2 * jj], sc0[2 * jj + 1]);
            W1[jj] = cvtpk_bf16(sc1[2 * jj], sc1[2 * jj + 1]);
        }
        {
            const unsigned short* vb = &vt_lds[bcur][0];
            union U16 { unsigned d[4]; bf16x8 v; };
#define PVSTEP(Warr, e, ks) { \
            unsigned x_  = Warr[4 * e],     y_  = Warr[4 * e + 2]; \
            unsigned x2_ = Warr[4 * e + 1], y2_ = Warr[4 * e + 3]; \
            asm volatile("v_permlane32_swap_b32 %0, %1" : "+v"(x_),  "+v"(y_)); \
            asm volatile("v_permlane32_swap_b32 %0, %1" : "+v"(x2_), "+v"(y2_)); \
            U16 pf; pf.d[0] = x_; pf.d[1] = x2_; pf.d[2] = y_; pf.d[3] = y2_; \
            bf16x8 av = *(const bf16x8*)(vb + offV[ks]); \
            acc = __builtin_amdgcn_mfma_f32_32x32x16_bf16(av, pf.v, acc, 0, 0, 0); }
            PVSTEP(W0, 0, 0)
            PVSTEP(W0, 1, 1)
            PVSTEP(W1, 0, 2)
            PVSTEP(W1, 1, 3)
#undef PVSTEP
        }

        // ---- subtile switch: emit A, reset state ----
        if (j == nA - 1) {
            EMIT(qrowA);
            acc = (f32x16){0,0,0,0,0,0,0,0,0,0,0,0,0,0,0,0};
            m = -1e30f; l = 0.f;
        }

        // ---- re-stage freed buffer with tile j+3 (guard LDS reads first) ----
        if (j + 3 < NT) {
            asm volatile("s_waitcnt lgkmcnt(0)" ::: "memory");
            const int jn = j + 3;
            STAGE(bcur, (jn < nA) ? jn : jn - nA);
        }
        // ---- switch Q fragments one step before tile-B scores are computed ----
        if (j == nA - 2) LOADQF(qrowB);

        if (j + 1 < NT) { sc0 = sn0; sc1 = sn1; }
        bcur = bnxt;
    }

    EMIT(qrowB);
}

// ============================================================
// K3: out = Ob @ Wo^T  (A bf16; B converted f32->bf16 in staging)
// ============================================================
__global__ __launch_bounds__(256) void proj_gemm_kernel(
    const unsigned short* __restrict__ Ob, const float* __restrict__ Wo,
    float* __restrict__ out)
{
    __shared__ __align__(16) unsigned short a_lds[64][200];
    __shared__ __align__(16) unsigned short b_lds[64][200];
    const int tid = threadIdx.x;
    const int wid = tid >> 6, lane = tid & 63, g = lane >> 4, lr = lane & 15;
    const int brow = blockIdx.x * 64;
    const int bcol = blockIdx.y * 64;

    #pragma unroll
    for (int c = 0; c < 6; ++c) {
        int idx = c * 256 + tid;
        int r = idx / 24, ch = idx % 24;
        *(uint4*)&a_lds[r][ch * 8] = *(const uint4*)&Ob[(size_t)(brow + r) * 192 + ch * 8];
    }
    #pragma unroll
    for (int c = 0; c < 12; ++c) {
        int idx = c * 256 + tid;
        int r = idx / 48, ch = idx % 48;
        float4 wv = *(const float4*)&Wo[(size_t)(bcol + r) * 192 + ch * 4];
        uint2 w2; w2.x = pk2(wv.x, wv.y); w2.y = pk2(wv.z, wv.w);
        *(uint2*)&b_lds[r][ch * 4] = w2;
    }
    __syncthreads();

    f32x4 acc[4];
    #pragma unroll
    for (int nc = 0; nc < 4; ++nc) acc[nc] = (f32x4){0.f, 0.f, 0.f, 0.f};
    #pragma unroll
    for (int kc = 0; kc < 6; ++kc) {
        bf16x8 af = *(const bf16x8*)&a_lds[wid * 16 + lr][kc * 32 + g * 8];
        #pragma unroll
        for (int nc = 0; nc < 4; ++nc) {
            bf16x8 bfr = *(const bf16x8*)&b_lds[nc * 16 + lr][kc * 32 + g * 8];
            acc[nc] = __builtin_amdgcn_mfma_f32_16x16x32_bf16(af, bfr, acc[nc], 0, 0, 0);
        }
    }

    #pragma unroll
    for (int nc = 0; nc < 4; ++nc) {
        int c = bcol + nc * 16 + lr;
        #pragma unroll
        for (int r = 0; r < 4; ++r) {
            int row = brow + wid * 16 + g * 4 + r;
            out[(size_t)row * 192 + c] = acc[nc][r];
        }
    }
}

// ============================================================
extern "C" void kernel_launch(void* const* d_in, const int* in_sizes, int n_in,
                              void* d_out, int out_size, void* d_ws, size_t ws_size,
                              hipStream_t stream) {
    const float* x     = (const float*)d_in[0];
    const float* Wq    = (const float*)d_in[1];
    const float* Wkv   = (const float*)d_in[2];
    const float* Wo    = (const float*)d_in[3];
    const float* alpha = (const float*)d_in[4];
    const float* beta  = (const float*)d_in[5];

    char* ws = (char*)d_ws;
    const size_t QA_BYTES = (size_t)B_N * 8 * S_LEN * KAUG * 2;   // 10,485,760
    const size_t KA_BYTES = (size_t)B_N * 4 * S_LEN * KAUG * 2;   //  5,242,880
    const size_t VT_BYTES = (size_t)B_N * 4 * 32 * S_LEN * 2;     //  1,048,576
    unsigned short* QA = (unsigned short*)ws;
    unsigned short* KA = (unsigned short*)(ws + QA_BYTES);
    unsigned short* VT = (unsigned short*)(ws + QA_BYTES + KA_BYTES);
    unsigned short* Ob = (unsigned short*)(ws + QA_BYTES + KA_BYTES + VT_BYTES);
    float* out = (float*)d_out;

    hipLaunchKernelGGL(prep_kernel, dim3(904), dim3(256), 0, stream,
                       x, Wq, Wkv, alpha, beta, QA, KA, VT);
    hipLaunchKernelGGL(attn_kernel, dim3(512), dim3(64), 0, stream,
                       QA, KA, VT, Ob);
    hipLaunchKernelGGL(proj_gemm_kernel, dim3(64, 3), dim3(256), 0, stream,
                       Ob, Wo, out);
}

// Round 8
// 70.927 us; speedup vs baseline: 1.1851x; 1.1851x over previous
//
#include <hip/hip_runtime.h>
#include <math.h>

// ---- problem constants ----
#define B_N    2
#define S_LEN  2048
#define DMODEL 192
#define LOG2E  1.44269504088896340736f

typedef __attribute__((ext_vector_type(8)))  short bf16x8;
typedef __attribute__((ext_vector_type(4)))  float f32x4;
typedef __attribute__((ext_vector_type(16))) float f32x16;

static __device__ __forceinline__ unsigned short f2bf(float f) {
    union { float f; unsigned u; } v; v.f = f;
    unsigned r = v.u + 0x7FFFu + ((v.u >> 16) & 1u);
    return (unsigned short)(r >> 16);
}
static __device__ __forceinline__ unsigned pk2(float a, float b) {
    return (unsigned)f2bf(a) | ((unsigned)f2bf(b) << 16);
}
static __device__ __forceinline__ unsigned cvtpk_bf16(float a, float b) {
    unsigned r;
    asm("v_cvt_pk_bf16_f32 %0, %1, %2" : "=v"(r) : "v"(a), "v"(b));
    return r;
}

// ============================================================
// K1: prep — blocks [0,384): QKV GEMM (f32->bf16 staged, MFMA),
// epilogue scatters q->Qh (alpha*SCALE*log2e), k->Kh, v->VT.
// blocks [384,896): phase sincos -> Phq (beta/64*log2e scaled) and
// Phk (raw), plus Qh/Kh pad zeroing.  [896,904): VT pad rows.
// ============================================================
__global__ __launch_bounds__(256) void prep_kernel(
    const float* __restrict__ x, const float* __restrict__ Wq,
    const float* __restrict__ Wkv, const float* __restrict__ alpha_p,
    const float* __restrict__ beta_p,
    unsigned short* __restrict__ Qh, unsigned short* __restrict__ Kh,
    unsigned short* __restrict__ Phq, unsigned short* __restrict__ Phk,
    unsigned short* __restrict__ VT)
{
    __shared__ __align__(16) unsigned short a_lds[64][200];
    __shared__ __align__(16) unsigned short b_lds[64][200];
    const int blk = blockIdx.x, tid = threadIdx.x;

    if (blk < 384) {
        const int wid = tid >> 6, lane = tid & 63, g = lane >> 4, lr = lane & 15;
        const int brow = (blk & 63) * 64;
        const int bcol = (blk >> 6) * 64;

        #pragma unroll
        for (int c = 0; c < 12; ++c) {
            int idx = c * 256 + tid;
            int r = idx / 48, ch = idx % 48;
            float4 v = *(const float4*)&x[(size_t)(brow + r) * 192 + ch * 4];
            uint2 w; w.x = pk2(v.x, v.y); w.y = pk2(v.z, v.w);
            *(uint2*)&a_lds[r][ch * 4] = w;
            int wr = bcol + r;
            const float* wsrc = (wr < 192) ? &Wq[(size_t)wr * 192 + ch * 4]
                                           : &Wkv[(size_t)(wr - 192) * 192 + ch * 4];
            float4 wv = *(const float4*)wsrc;
            uint2 w2; w2.x = pk2(wv.x, wv.y); w2.y = pk2(wv.z, wv.w);
            *(uint2*)&b_lds[r][ch * 4] = w2;
        }
        __syncthreads();

        f32x4 acc[4];
        #pragma unroll
        for (int nc = 0; nc < 4; ++nc) acc[nc] = (f32x4){0.f, 0.f, 0.f, 0.f};
        #pragma unroll
        for (int kc = 0; kc < 6; ++kc) {
            bf16x8 af = *(const bf16x8*)&a_lds[wid * 16 + lr][kc * 32 + g * 8];
            #pragma unroll
            for (int nc = 0; nc < 4; ++nc) {
                bf16x8 bfr = *(const bf16x8*)&b_lds[nc * 16 + lr][kc * 32 + g * 8];
                acc[nc] = __builtin_amdgcn_mfma_f32_16x16x32_bf16(af, bfr, acc[nc], 0, 0, 0);
            }
        }

        const float qs = alpha_p[0] * 0.20412414523193150818f * LOG2E;
        #pragma unroll
        for (int nc = 0; nc < 4; ++nc) {
            int c = bcol + nc * 16 + lr;
            #pragma unroll
            for (int r = 0; r < 4; ++r) {
                int row = brow + wid * 16 + g * 4 + r;
                int b = row >> 11, s = row & (S_LEN - 1);
                float v = acc[nc][r];
                if (c < 192) {
                    int h = c / 24, d = c - 24 * h;
                    Qh[((size_t)(b * 8 + h) * S_LEN + s) * 32 + d] = f2bf(v * qs);
                } else if (c < 288) {
                    int cc = c - 192, kvh = cc / 24, d = cc - 24 * kvh;
                    Kh[((size_t)(b * 4 + kvh) * S_LEN + s) * 32 + d] = f2bf(v);
                } else {
                    int cc = c - 288, kvh = cc / 24, d = cc - 24 * kvh;
                    VT[((size_t)(b * 4 + kvh) * 32 + d) * S_LEN + s] = f2bf(v);
                }
            }
        }
    } else if (blk < 896) {
        const int pblk = blk - 384;
        const int r = tid >> 5, i = tid & 31;
        const int row = pblk * 8 + r;
        const int b = row >> 11, s = row & (S_LEN - 1);
        const float bf = beta_p[0] * (1.0f / 64.0f) * LOG2E;
        float2 p = *(const float2*)&x[(size_t)row * DMODEL + 128 + 2 * i];
        float s0, c0, s1, c1;
        sincosf(p.x, &s0, &c0);
        sincosf(p.y, &s1, &c1);
        unsigned short* phq = Phq + ((size_t)b * S_LEN + s) * 128;
        unsigned short* phk = Phk + ((size_t)b * S_LEN + s) * 128;
        *(unsigned*)(phq + 2 * i)      = pk2(c0 * bf, c1 * bf);
        *(unsigned*)(phq + 64 + 2 * i) = pk2(s0 * bf, s1 * bf);
        *(unsigned*)(phk + 2 * i)      = pk2(c0, c1);
        *(unsigned*)(phk + 64 + 2 * i) = pk2(s0, s1);
        if (i < 12) {
            uint4 z = {0u, 0u, 0u, 0u};
            unsigned short* base = (i < 8)
                ? Qh + ((size_t)(b * 8 + i) * S_LEN + s) * 32 + 24
                : Kh + ((size_t)(b * 4 + (i - 8)) * S_LEN + s) * 32 + 24;
            *(uint4*)base = z;
        }
    } else {
        const int j = blk - 896;
        unsigned short* base = VT + ((size_t)j * 32 + 24) * S_LEN;
        uint4 z = {0u, 0u, 0u, 0u};
        #pragma unroll
        for (int c = 0; c < 8; ++c)
            *(uint4*)(base + (size_t)(c * 256 + tid) * 8) = z;
    }
}

// ============================================================
// K2: key-split attention — 2048 one-wave blocks, ZERO LDS.
// bid&7 = (b,kvh) [XCD group]; u=bid>>3: s=63-(u>>2) (longest first),
// hq=(u>>1)&1, half=u&1.  Wave owns q rows [32s,32s+32), key-tiles
// [half? r/2 : 0, half? r : r/2) with r=s+1 tiles of 32 keys.
// All operands (K,phase,V^T) loaded global->VGPR (L2-resident),
// double-buffered via manual 2x unroll.  QK = 2 interleaved 5-MFMA
// chains; softmax in-register log2-domain with defer-max; PV B-frag
// via cvt_pk + permlane32_swap.  Emits partial (m,l,acc) per block.
// ============================================================
struct KB { bf16x8 kh0, kh1, ph0, ph1, ph2, ph3, ph4, ph5, ph6, ph7, vt0, vt1; };

__global__ __launch_bounds__(64, 2) void attn_kernel(
    const unsigned short* __restrict__ Qh, const unsigned short* __restrict__ Kh,
    const unsigned short* __restrict__ Phq, const unsigned short* __restrict__ Phk,
    const unsigned short* __restrict__ VT,
    float* __restrict__ pacc, float* __restrict__ pml)
{
    const int lane = threadIdx.x & 63;
    const int hi = lane >> 5, c31 = lane & 31;

    const int bid = blockIdx.x;
    const int grp = bid & 7, b = grp >> 2, kvh = grp & 3;
    const int u = bid >> 3;
    const int s = 63 - (u >> 2);
    const int hq = (u >> 1) & 1, half = u & 1;
    const int h = 2 * kvh + hq;
    const int r = s + 1, r0 = r >> 1;
    const int nt = half ? (r - r0) : r0;
    const int tb = half ? r0 : 0;
    const int qrow = s * 32 + c31;

    const unsigned short* kh_g  = Kh  + (size_t)(b * 4 + kvh) * S_LEN * 32 + c31 * 32 + hi * 8;
    const unsigned short* phk_g = Phk + (size_t)b * S_LEN * 128 + c31 * 128 + hi * 8;
    const unsigned short* vt_g  = VT  + (size_t)(b * 4 + kvh) * 32 * S_LEN + c31 * S_LEN + hi * 8;

    f32x16 acc = {0,0,0,0,0,0,0,0,0,0,0,0,0,0,0,0};
    float m = -1e30f, l = 0.f;

    if (nt > 0) {
        // ---- Q fragments (10 b128, stay in regs) ----
        bf16x8 qf[10];
        {
            const unsigned short* qh = Qh + ((size_t)(b * 8 + h) * S_LEN + qrow) * 32 + hi * 8;
            const unsigned short* pq = Phq + ((size_t)b * S_LEN + qrow) * 128 + hi * 8;
            qf[0] = *(const bf16x8*)qh;
            qf[1] = *(const bf16x8*)(qh + 16);
            #pragma unroll
            for (int c = 0; c < 8; ++c) qf[2 + c] = *(const bf16x8*)(pq + c * 16);
        }

        auto LOADK = [&](int t) {
            KB kb;
            const unsigned short* kg = kh_g + (size_t)t * 1024;
            const unsigned short* pg = phk_g + (size_t)t * 4096;
            const unsigned short* vg = vt_g + t * 32;
            kb.kh0 = *(const bf16x8*)kg;
            kb.kh1 = *(const bf16x8*)(kg + 16);
            kb.ph0 = *(const bf16x8*)pg;
            kb.ph1 = *(const bf16x8*)(pg + 16);
            kb.ph2 = *(const bf16x8*)(pg + 32);
            kb.ph3 = *(const bf16x8*)(pg + 48);
            kb.ph4 = *(const bf16x8*)(pg + 64);
            kb.ph5 = *(const bf16x8*)(pg + 80);
            kb.ph6 = *(const bf16x8*)(pg + 96);
            kb.ph7 = *(const bf16x8*)(pg + 112);
            kb.vt0 = *(const bf16x8*)vg;
            kb.vt1 = *(const bf16x8*)(vg + 16);
            return kb;
        };

        auto STEP = [&](const KB& kb, bool diag) {
            f32x16 sa = {0,0,0,0,0,0,0,0,0,0,0,0,0,0,0,0};
            f32x16 sb = {0,0,0,0,0,0,0,0,0,0,0,0,0,0,0,0};
            sa = __builtin_amdgcn_mfma_f32_32x32x16_bf16(kb.kh0, qf[0], sa, 0, 0, 0);
            sb = __builtin_amdgcn_mfma_f32_32x32x16_bf16(kb.kh1, qf[1], sb, 0, 0, 0);
            sa = __builtin_amdgcn_mfma_f32_32x32x16_bf16(kb.ph0, qf[2], sa, 0, 0, 0);
            sb = __builtin_amdgcn_mfma_f32_32x32x16_bf16(kb.ph1, qf[3], sb, 0, 0, 0);
            sa = __builtin_amdgcn_mfma_f32_32x32x16_bf16(kb.ph2, qf[4], sa, 0, 0, 0);
            sb = __builtin_amdgcn_mfma_f32_32x32x16_bf16(kb.ph3, qf[5], sb, 0, 0, 0);
            sa = __builtin_amdgcn_mfma_f32_32x32x16_bf16(kb.ph4, qf[6], sa, 0, 0, 0);
            sb = __builtin_amdgcn_mfma_f32_32x32x16_bf16(kb.ph5, qf[7], sb, 0, 0, 0);
            sa = __builtin_amdgcn_mfma_f32_32x32x16_bf16(kb.ph6, qf[8], sa, 0, 0, 0);
            sb = __builtin_amdgcn_mfma_f32_32x32x16_bf16(kb.ph7, qf[9], sb, 0, 0, 0);
            float sc[16];
            #pragma unroll
            for (int i = 0; i < 16; ++i) sc[i] = sa[i] + sb[i];
            if (diag) {
                #pragma unroll
                for (int i = 0; i < 16; ++i) {
                    int kr = (i & 3) + 8 * (i >> 2) + 4 * hi;
                    if (kr > c31) sc[i] = -1e30f;
                }
            }
            // ---- softmax (tree + cross-half shfl, defer-max) ----
            float t4[4];
            #pragma unroll
            for (int i = 0; i < 4; ++i)
                t4[i] = fmaxf(fmaxf(sc[i], sc[i + 4]), fmaxf(sc[i + 8], sc[i + 12]));
            float tmax = fmaxf(fmaxf(t4[0], t4[1]), fmaxf(t4[2], t4[3]));
            tmax = fmaxf(tmax, __shfl_xor(tmax, 32, 64));
            if (!__all(tmax <= m + 8.f)) {
                float mnew = fmaxf(m, tmax);
                float corr = __builtin_amdgcn_exp2f(m - mnew);
                m = mnew;
                l *= corr;
                #pragma unroll
                for (int i = 0; i < 16; ++i) acc[i] *= corr;
            }
            #pragma unroll
            for (int i = 0; i < 16; ++i) sc[i] = __builtin_amdgcn_exp2f(sc[i] - m);
            float u4[4];
            #pragma unroll
            for (int i = 0; i < 4; ++i)
                u4[i] = (sc[i] + sc[i + 4]) + (sc[i + 8] + sc[i + 12]);
            float ts = (u4[0] + u4[1]) + (u4[2] + u4[3]);
            ts += __shfl_xor(ts, 32, 64);
            l += ts;
            // ---- pack P, PV (A = V^T frags from regs) ----
            unsigned W[8];
            #pragma unroll
            for (int i = 0; i < 8; ++i) W[i] = cvtpk_bf16(sc[2 * i], sc[2 * i + 1]);
            union U16 { unsigned d[4]; bf16x8 v; };
#define PVSTEP(e, AV) { \
            unsigned x_  = W[4 * e],     y_  = W[4 * e + 2]; \
            unsigned x2_ = W[4 * e + 1], y2_ = W[4 * e + 3]; \
            asm volatile("v_permlane32_swap_b32 %0, %1" : "+v"(x_),  "+v"(y_)); \
            asm volatile("v_permlane32_swap_b32 %0, %1" : "+v"(x2_), "+v"(y2_)); \
            U16 pf; pf.d[0] = x_; pf.d[1] = x2_; pf.d[2] = y_; pf.d[3] = y2_; \
            acc = __builtin_amdgcn_mfma_f32_32x32x16_bf16(AV, pf.v, acc, 0, 0, 0); }
            PVSTEP(0, kb.vt0)
            PVSTEP(1, kb.vt1)
#undef PVSTEP
        };

        // ---- 2x-unrolled pipeline (no runtime-indexed reg arrays) ----
        KB kA = LOADK(tb);
        int j = 0;
        for (; j + 2 <= nt; j += 2) {
            KB kB = LOADK(tb + j + 1);
            STEP(kA, half && (j == nt - 1));
            if (j + 2 < nt) kA = LOADK(tb + j + 2);
            STEP(kB, half && (j + 1 == nt - 1));
        }
        if (j < nt) STEP(kA, half != 0);   // odd tail is always the last tile
    }

    // ---- emit partials ----
    {
        float* pa = pacc + (size_t)bid * 1024 + lane * 16;
        #pragma unroll
        for (int k = 0; k < 4; ++k) {
            f32x4 v = {acc[4 * k], acc[4 * k + 1], acc[4 * k + 2], acc[4 * k + 3]};
            *(f32x4*)(pa + 4 * k) = v;
        }
        if (hi == 0) {
            float2 ml = {m, l};
            *(float2*)(pml + (size_t)bid * 64 + c31 * 2) = ml;
        }
    }
}

// ============================================================
// K2b: combine — 1024 one-wave blocks; merge the two key-split
// partials of each (b,h,s) and write Ob bf16.
// ============================================================
__global__ __launch_bounds__(64) void combine_kernel(
    const float* __restrict__ pacc, const float* __restrict__ pml,
    unsigned short* __restrict__ Ob)
{
    const int lane = threadIdx.x & 63;
    const int hi = lane >> 5, c31 = lane & 31;
    const int bid = blockIdx.x;
    const int b = bid >> 9, h = (bid >> 6) & 7, s = bid & 63;

    const int ub = (((63 - s) << 2) | ((h & 1) << 1));
    const int gb = (b * 4 + (h >> 1));
    const int blk0 = (ub | 0) * 8 + gb;
    const int blk1 = (ub | 1) * 8 + gb;

    float2 ml0 = *(const float2*)(pml + (size_t)blk0 * 64 + c31 * 2);
    float2 ml1 = *(const float2*)(pml + (size_t)blk1 * 64 + c31 * 2);
    float M = fmaxf(ml0.x, ml1.x);
    float w0 = __builtin_amdgcn_exp2f(ml0.x - M);
    float w1 = __builtin_amdgcn_exp2f(ml1.x - M);
    float L = ml0.y * w0 + ml1.y * w1;
    float inv = 1.0f / L;

    const float* a0 = pacc + (size_t)blk0 * 1024 + lane * 16;
    const float* a1 = pacc + (size_t)blk1 * 1024 + lane * 16;
    float o[16];
    #pragma unroll
    for (int k = 0; k < 4; ++k) {
        f32x4 v0 = *(const f32x4*)(a0 + 4 * k);
        f32x4 v1 = *(const f32x4*)(a1 + 4 * k);
        #pragma unroll
        for (int i = 0; i < 4; ++i)
            o[4 * k + i] = (v0[i] * w0 + v1[i] * w1) * inv;
    }

    unsigned short* ob = Ob + ((size_t)b * S_LEN + s * 32 + c31) * DMODEL + h * 24 + 4 * hi;
    #pragma unroll
    for (int k = 0; k < 3; ++k) {
        *(unsigned*)(ob + 8 * k)     = pk2(o[4 * k],     o[4 * k + 1]);
        *(unsigned*)(ob + 8 * k + 2) = pk2(o[4 * k + 2], o[4 * k + 3]);
    }
}

// ============================================================
// K3: out = Ob @ Wo^T  (A bf16; B converted f32->bf16 in staging)
// ============================================================
__global__ __launch_bounds__(256) void proj_gemm_kernel(
    const unsigned short* __restrict__ Ob, const float* __restrict__ Wo,
    float* __restrict__ out)
{
    __shared__ __align__(16) unsigned short a_lds[64][200];
    __shared__ __align__(16) unsigned short b_lds[64][200];
    const int tid = threadIdx.x;
    const int wid = tid >> 6, lane = tid & 63, g = lane >> 4, lr = lane & 15;
    const int brow = blockIdx.x * 64;
    const int bcol = blockIdx.y * 64;

    #pragma unroll
    for (int c = 0; c < 6; ++c) {
        int idx = c * 256 + tid;
        int r = idx / 24, ch = idx % 24;
        *(uint4*)&a_lds[r][ch * 8] = *(const uint4*)&Ob[(size_t)(brow + r) * 192 + ch * 8];
    }
    #pragma unroll
    for (int c = 0; c < 12; ++c) {
        int idx = c * 256 + tid;
        int r = idx / 48, ch = idx % 48;
        float4 wv = *(const float4*)&Wo[(size_t)(bcol + r) * 192 + ch * 4];
        uint2 w2; w2.x = pk2(wv.x, wv.y); w2.y = pk2(wv.z, wv.w);
        *(uint2*)&b_lds[r][ch * 4] = w2;
    }
    __syncthreads();

    f32x4 acc[4];
    #pragma unroll
    for (int nc = 0; nc < 4; ++nc) acc[nc] = (f32x4){0.f, 0.f, 0.f, 0.f};
    #pragma unroll
    for (int kc = 0; kc < 6; ++kc) {
        bf16x8 af = *(const bf16x8*)&a_lds[wid * 16 + lr][kc * 32 + g * 8];
        #pragma unroll
        for (int nc = 0; nc < 4; ++nc) {
            bf16x8 bfr = *(const bf16x8*)&b_lds[nc * 16 + lr][kc * 32 + g * 8];
            acc[nc] = __builtin_amdgcn_mfma_f32_16x16x32_bf16(af, bfr, acc[nc], 0, 0, 0);
        }
    }

    #pragma unroll
    for (int nc = 0; nc < 4; ++nc) {
        int c = bcol + nc * 16 + lr;
        #pragma unroll
        for (int r = 0; r < 4; ++r) {
            int row = brow + wid * 16 + g * 4 + r;
            out[(size_t)row * 192 + c] = acc[nc][r];
        }
    }
}

// ============================================================
extern "C" void kernel_launch(void* const* d_in, const int* in_sizes, int n_in,
                              void* d_out, int out_size, void* d_ws, size_t ws_size,
                              hipStream_t stream) {
    const float* x     = (const float*)d_in[0];
    const float* Wq    = (const float*)d_in[1];
    const float* Wkv   = (const float*)d_in[2];
    const float* Wo    = (const float*)d_in[3];
    const float* alpha = (const float*)d_in[4];
    const float* beta  = (const float*)d_in[5];

    char* ws = (char*)d_ws;
    const size_t QH_BYTES  = (size_t)B_N * 8 * S_LEN * 32 * 2;    // 2,097,152
    const size_t KH_BYTES  = (size_t)B_N * 4 * S_LEN * 32 * 2;    // 1,048,576
    const size_t PH_BYTES  = (size_t)B_N * S_LEN * 128 * 2;       // 1,048,576
    const size_t VT_BYTES  = (size_t)B_N * 4 * 32 * S_LEN * 2;    // 1,048,576
    const size_t OB_BYTES  = (size_t)B_N * S_LEN * DMODEL * 2;    // 1,572,864
    const size_t PACC_BYTES = (size_t)2048 * 1024 * 4;            // 8,388,608

    unsigned short* Qh  = (unsigned short*)ws;
    unsigned short* Kh  = (unsigned short*)(ws + QH_BYTES);
    unsigned short* Phq = (unsigned short*)(ws + QH_BYTES + KH_BYTES);
    unsigned short* Phk = (unsigned short*)(ws + QH_BYTES + KH_BYTES + PH_BYTES);
    unsigned short* VT  = (unsigned short*)(ws + QH_BYTES + KH_BYTES + 2 * PH_BYTES);
    unsigned short* Ob  = (unsigned short*)(ws + QH_BYTES + KH_BYTES + 2 * PH_BYTES + VT_BYTES);
    float* pacc = (float*)(ws + QH_BYTES + KH_BYTES + 2 * PH_BYTES + VT_BYTES + OB_BYTES);
    float* pml  = (float*)(ws + QH_BYTES + KH_BYTES + 2 * PH_BYTES + VT_BYTES + OB_BYTES + PACC_BYTES);
    float* out = (float*)d_out;

    hipLaunchKernelGGL(prep_kernel, dim3(904), dim3(256), 0, stream,
                       x, Wq, Wkv, alpha, beta, Qh, Kh, Phq, Phk, VT);
    hipLaunchKernelGGL(attn_kernel, dim3(2048), dim3(64), 0, stream,
                       Qh, Kh, Phq, Phk, VT, pacc, pml);
    hipLaunchKernelGGL(combine_kernel, dim3(1024), dim3(64), 0, stream,
                       pacc, pml, Ob);
    hipLaunchKernelGGL(proj_gemm_kernel, dim3(64, 3), dim3(256), 0, stream,
                       Ob, Wo, out);
}